// Round 4
// baseline (21411.057 us; speedup 1.0000x reference)
//
#include <hip/hip_runtime.h>
#include <math.h>

#define N_NODES 50000
#define N_EDGES 1600000
#define DIN 1024
#define H 256
#define L_LAYERS 64
#define ALPHA 0.2f

// Keep a symbol with the exact problem identifier.
__global__ void GCNIIForDialog_18923625906417_kernel() {}

// ---------- utility: zero ints ----------
__global__ __launch_bounds__(256) void k_zero(int* __restrict__ p, int n) {
  int i = blockIdx.x * 256 + threadIdx.x;
  if (i < n) p[i] = 0;
}

// ---------- graph build ----------
__global__ __launch_bounds__(256) void k_count(const int* __restrict__ dst, int* __restrict__ cnt) {
  int e = blockIdx.x * 256 + threadIdx.x;
  if (e < N_EDGES) atomicAdd(&cnt[dst[e]], 1);
}

__global__ __launch_bounds__(256) void k_dinv(const int* __restrict__ cnt, float* __restrict__ dinv) {
  int i = blockIdx.x * 256 + threadIdx.x;
  if (i < N_NODES) dinv[i] = 1.0f / sqrtf((float)(cnt[i] + 1));  // +1 self loop
}

__global__ __launch_bounds__(1024) void k_scan(const int* __restrict__ cnt, int* __restrict__ offs) {
  const int CH = (N_NODES + 1023) / 1024;  // 49
  __shared__ int sums[1024];
  int t = threadIdx.x;
  int lo = t * CH, hi = lo + CH;
  if (hi > N_NODES) hi = N_NODES;
  int s = 0;
  for (int i = lo; i < hi; ++i) s += cnt[i];
  sums[t] = s;
  __syncthreads();
  for (int d = 1; d < 1024; d <<= 1) {
    int v = (t >= d) ? sums[t - d] : 0;
    __syncthreads();
    sums[t] += v;
    __syncthreads();
  }
  int run = (t == 0) ? 0 : sums[t - 1];
  for (int i = lo; i < hi; ++i) { offs[i] = run; run += cnt[i]; }
  if (t == 0) offs[N_NODES] = sums[1023];
}

__global__ __launch_bounds__(256) void k_scatter(const int* __restrict__ src, const int* __restrict__ dst,
    const int* __restrict__ offs, int* __restrict__ cursor, const float* __restrict__ dinv,
    int* __restrict__ col, float* __restrict__ w) {
  int e = blockIdx.x * 256 + threadIdx.x;
  if (e >= N_EDGES) return;
  int sN = src[e], dN = dst[e];
  int pos = offs[dN] + atomicAdd(&cursor[dN], 1);
  col[pos] = sN;
  w[pos] = dinv[sN] * dinv[dN];
}

// ---------- SpMM + residual: s = 0.8 * (A_hat h) + 0.2 * h0 ----------
__global__ __launch_bounds__(256) void k_spmm(
    const float* __restrict__ h, const float* __restrict__ h0,
    const int* __restrict__ offs, const int* __restrict__ col, const float* __restrict__ w,
    const float* __restrict__ dinv, float* __restrict__ s)
{
  int wid = threadIdx.x >> 6, lane = threadIdx.x & 63;
  int node = blockIdx.x * 4 + wid;
  if (node >= N_NODES) return;
  int c4 = lane * 4;
  float di = dinv[node];
  float di2 = di * di;
  float4 hv = *(const float4*)(h + (size_t)node * H + c4);  // self loop
  float ax = di2 * hv.x, ay = di2 * hv.y, az = di2 * hv.z, aw = di2 * hv.w;
  int e = offs[node], e1 = offs[node + 1];
  for (; e + 2 <= e1; e += 2) {
    int j0 = col[e], j1 = col[e + 1];
    float w0 = w[e], w1 = w[e + 1];
    float4 v0 = *(const float4*)(h + (size_t)j0 * H + c4);
    float4 v1 = *(const float4*)(h + (size_t)j1 * H + c4);
    ax += w0 * v0.x; ay += w0 * v0.y; az += w0 * v0.z; aw += w0 * v0.w;
    ax += w1 * v1.x; ay += w1 * v1.y; az += w1 * v1.z; aw += w1 * v1.w;
  }
  if (e < e1) {
    int j0 = col[e];
    float w0 = w[e];
    float4 v0 = *(const float4*)(h + (size_t)j0 * H + c4);
    ax += w0 * v0.x; ay += w0 * v0.y; az += w0 * v0.z; aw += w0 * v0.w;
  }
  float4 h0v = *(const float4*)(h0 + (size_t)node * H + c4);
  float4 sv;
  sv.x = (1.0f - ALPHA) * ax + ALPHA * h0v.x;
  sv.y = (1.0f - ALPHA) * ay + ALPHA * h0v.y;
  sv.z = (1.0f - ALPHA) * az + ALPHA * h0v.z;
  sv.w = (1.0f - ALPHA) * aw + ALPHA * h0v.w;
  *(float4*)(s + (size_t)node * H + c4) = sv;
}

// ---------- VALU GEMM: out = A[M,K] @ W[K,256], 64x64 tile, 4x4 per thread ----------
// mode 0 (proj):  out0 = out1 = acc + bias[c]
// mode 1 (layer): out0 = relu((1-beta)*Sin + beta*acc)
__global__ __launch_bounds__(256) void k_vgemm(
    const float* __restrict__ A, const float* __restrict__ W, int K,
    const float* __restrict__ Sin, const float* __restrict__ bias,
    float* __restrict__ out0, float* __restrict__ out1, float beta, int mode)
{
  __shared__ float As[16][68];  // [k][row], +4 pad
  __shared__ float Ws[16][68];  // [k][col]
  int tid = threadIdx.x;
  int mBase = blockIdx.x * 64, nBase = blockIdx.y * 64;
  int ty4 = (tid >> 4) * 4;   // row group within tile
  int tx4 = (tid & 15) * 4;   // col group
  int srow = tid >> 2;            // 0..63
  int skseg = (tid & 3) * 4;      // 0,4,8,12
  int wkk = tid >> 4;             // 0..15
  int wcseg = (tid & 15) * 4;     // 0..60
  float acc[4][4];
#pragma unroll
  for (int i = 0; i < 4; ++i)
#pragma unroll
    for (int j = 0; j < 4; ++j) acc[i][j] = 0.0f;

  for (int k0 = 0; k0 < K; k0 += 16) {
    // stage A (64 rows x 16 k), transposed to [k][row]
    float4 av4 = make_float4(0.f, 0.f, 0.f, 0.f);
    int grow = mBase + srow;
    if (grow < N_NODES) av4 = *(const float4*)(A + (size_t)grow * K + k0 + skseg);
    As[skseg + 0][srow] = av4.x;
    As[skseg + 1][srow] = av4.y;
    As[skseg + 2][srow] = av4.z;
    As[skseg + 3][srow] = av4.w;
    // stage W (16 k x 64 cols)
    *(float4*)&Ws[wkk][wcseg] = *(const float4*)(W + (size_t)(k0 + wkk) * H + nBase + wcseg);
    __syncthreads();
#pragma unroll
    for (int kk = 0; kk < 16; ++kk) {
      float4 a4 = *(const float4*)&As[kk][ty4];
      float4 w4 = *(const float4*)&Ws[kk][tx4];
      float av[4] = {a4.x, a4.y, a4.z, a4.w};
      float wv[4] = {w4.x, w4.y, w4.z, w4.w};
#pragma unroll
      for (int i = 0; i < 4; ++i)
#pragma unroll
        for (int j = 0; j < 4; ++j) acc[i][j] += av[i] * wv[j];
    }
    __syncthreads();
  }

#pragma unroll
  for (int i = 0; i < 4; ++i) {
    int row = mBase + ty4 + i;
    if (row >= N_NODES) break;
#pragma unroll
    for (int j = 0; j < 4; ++j) {
      int colg = nBase + tx4 + j;
      size_t idx = (size_t)row * H + colg;
      if (mode == 0) {
        float v = acc[i][j] + bias[colg];
        out0[idx] = v;
        out1[idx] = v;
      } else {
        float v = (1.0f - beta) * Sin[idx] + beta * acc[i][j];
        out0[idx] = fmaxf(v, 0.0f);
      }
    }
  }
}

// ---------- classifier: out[n, 0..3] = h[n,:] @ clsW + clsb ----------
__global__ __launch_bounds__(256) void k_cls(const float* __restrict__ h,
    const float* __restrict__ W, const float* __restrict__ b, float* __restrict__ out)
{
  int wid = threadIdx.x >> 6, lane = threadIdx.x & 63;
  int node = blockIdx.x * 4 + wid;
  if (node >= N_NODES) return;
  float a0 = 0, a1 = 0, a2 = 0, a3 = 0;
  for (int t = lane; t < H; t += 64) {
    float hv = h[(size_t)node * H + t];
    a0 += hv * W[t * 4 + 0];
    a1 += hv * W[t * 4 + 1];
    a2 += hv * W[t * 4 + 2];
    a3 += hv * W[t * 4 + 3];
  }
#pragma unroll
  for (int off = 32; off > 0; off >>= 1) {
    a0 += __shfl_down(a0, off);
    a1 += __shfl_down(a1, off);
    a2 += __shfl_down(a2, off);
    a3 += __shfl_down(a3, off);
  }
  if (lane == 0) {
    float4 o;
    o.x = a0 + b[0];
    o.y = a1 + b[1];
    o.z = a2 + b[2];
    o.w = a3 + b[3];
    *(float4*)(out + (size_t)node * 4) = o;
  }
}

extern "C" void kernel_launch(void* const* d_in, const int* in_sizes, int n_in,
                              void* d_out, int out_size, void* d_ws, size_t ws_size,
                              hipStream_t stream) {
  (void)in_sizes; (void)n_in; (void)out_size; (void)ws_size;
  const float* x     = (const float*)d_in[0];
  const int*   ei    = (const int*)d_in[1];
  const float* projW = (const float*)d_in[2];
  const float* projB = (const float*)d_in[3];
  const float* wts   = (const float*)d_in[4];
  const float* clsW  = (const float*)d_in[5];
  const float* clsB  = (const float*)d_in[6];
  float* out = (float*)d_out;

  char* ws = (char*)d_ws;
  size_t off = 0;
  auto alloc = [&](size_t bytes) -> void* {
    void* p = ws + off;
    off = (off + bytes + 255) & ~(size_t)255;
    return p;
  };
  int*   cntcur = (int*)alloc((size_t)N_NODES * 2 * 4);
  int*   cnt    = cntcur;
  int*   cursor = cntcur + N_NODES;
  int*   offs   = (int*)alloc((size_t)(N_NODES + 1) * 4);
  float* dinv   = (float*)alloc((size_t)N_NODES * 4);
  int*   col    = (int*)alloc((size_t)N_EDGES * 4);
  float* w      = (float*)alloc((size_t)N_EDGES * 4);
  float* h0     = (float*)alloc((size_t)N_NODES * H * 4);
  float* hA     = (float*)alloc((size_t)N_NODES * H * 4);
  float* hB     = (float*)alloc((size_t)N_NODES * H * 4);

  const int* src = ei;
  const int* dst = ei + N_EDGES;

  k_zero<<<(N_NODES * 2 + 255) / 256, 256, 0, stream>>>(cntcur, N_NODES * 2);
  k_count<<<(N_EDGES + 255) / 256, 256, 0, stream>>>(dst, cnt);
  k_dinv<<<(N_NODES + 255) / 256, 256, 0, stream>>>(cnt, dinv);
  k_scan<<<1, 1024, 0, stream>>>(cnt, offs);
  k_scatter<<<(N_EDGES + 255) / 256, 256, 0, stream>>>(src, dst, offs, cursor, dinv, col, w);

  dim3 gg((N_NODES + 63) / 64, H / 64);
  // projection: h0 = hA = x @ projW + b
  k_vgemm<<<gg, 256, 0, stream>>>(x, projW, DIN, nullptr, projB, hA, h0, 0.0f, 0);

  for (int l = 0; l < L_LAYERS; ++l) {
    k_spmm<<<(N_NODES + 3) / 4, 256, 0, stream>>>(hA, h0, offs, col, w, dinv, hB);
    float beta = logf(0.5f / (float)(l + 1) + 1.0f);
    k_vgemm<<<gg, 256, 0, stream>>>(hB, wts + (size_t)l * H * H, H,
                                    hB, nullptr, hA, nullptr, beta, 1);
  }
  k_cls<<<(N_NODES + 3) / 4, 256, 0, stream>>>(hA, clsW, clsB, out);
}

// Round 5
// 12514.266 us; speedup vs baseline: 1.7109x; 1.7109x over previous
//
#include <hip/hip_runtime.h>
#include <math.h>

#define N_NODES 50000
#define N_EDGES 1600000
#define DIN 1024
#define H 256
#define L_LAYERS 64
#define ALPHA 0.2f

typedef unsigned short u16;                                   // bf16 storage
typedef short short8 __attribute__((ext_vector_type(8)));     // MFMA A/B frag (8 bf16)
typedef float f32x4 __attribute__((ext_vector_type(4)));      // MFMA C/D frag
typedef unsigned int u32x4 __attribute__((ext_vector_type(4)));

__device__ inline float b2f(u16 h) { return __uint_as_float(((unsigned)h) << 16); }
__device__ inline u16 f2b(float f) {
  unsigned u = __float_as_uint(f);
  unsigned r = u + 0x7FFFu + ((u >> 16) & 1u);   // round-to-nearest-even
  return (u16)(r >> 16);
}

// Keep a symbol with the exact problem identifier.
__global__ void GCNIIForDialog_18923625906417_kernel() {}

// ---------- utility: zero ints ----------
__global__ __launch_bounds__(256) void k_zero(int* __restrict__ p, int n) {
  int i = blockIdx.x * 256 + threadIdx.x;
  if (i < n) p[i] = 0;
}

// ---------- graph build ----------
__global__ __launch_bounds__(256) void k_count(const int* __restrict__ dst, int* __restrict__ cnt) {
  int e = blockIdx.x * 256 + threadIdx.x;
  if (e < N_EDGES) atomicAdd(&cnt[dst[e]], 1);
}

__global__ __launch_bounds__(256) void k_dinv(const int* __restrict__ cnt, float* __restrict__ dinv) {
  int i = blockIdx.x * 256 + threadIdx.x;
  if (i < N_NODES) dinv[i] = 1.0f / sqrtf((float)(cnt[i] + 1));  // +1 self loop
}

__global__ __launch_bounds__(1024) void k_scan(const int* __restrict__ cnt, int* __restrict__ offs) {
  const int CH = (N_NODES + 1023) / 1024;  // 49
  __shared__ int sums[1024];
  int t = threadIdx.x;
  int lo = t * CH, hi = lo + CH;
  if (hi > N_NODES) hi = N_NODES;
  int s = 0;
  for (int i = lo; i < hi; ++i) s += cnt[i];
  sums[t] = s;
  __syncthreads();
  for (int d = 1; d < 1024; d <<= 1) {
    int v = (t >= d) ? sums[t - d] : 0;
    __syncthreads();
    sums[t] += v;
    __syncthreads();
  }
  int run = (t == 0) ? 0 : sums[t - 1];
  for (int i = lo; i < hi; ++i) { offs[i] = run; run += cnt[i]; }
  if (t == 0) offs[N_NODES] = sums[1023];
}

__global__ __launch_bounds__(256) void k_scatter(const int* __restrict__ src, const int* __restrict__ dst,
    const int* __restrict__ offs, int* __restrict__ cursor, const float* __restrict__ dinv,
    int* __restrict__ col, float* __restrict__ w) {
  int e = blockIdx.x * 256 + threadIdx.x;
  if (e >= N_EDGES) return;
  int sN = src[e], dN = dst[e];
  int pos = offs[dN] + atomicAdd(&cursor[dN], 1);
  col[pos] = sN;
  w[pos] = dinv[sN] * dinv[dN];
}

// ---------- W prep: WT[l][n][k] = (bf16) W[l][k][n] ----------
__global__ void k_wtr(const float* __restrict__ Win, u16* __restrict__ Wout) {
  __shared__ float tile[32][33];
  size_t base = (size_t)blockIdx.z * H * H;
  int n0 = blockIdx.x * 32, k0 = blockIdx.y * 32;
  for (int i = threadIdx.y; i < 32; i += 8)
    tile[i][threadIdx.x] = Win[base + (size_t)(k0 + i) * H + n0 + threadIdx.x];
  __syncthreads();
  for (int i = threadIdx.y; i < 32; i += 8)
    Wout[base + (size_t)(n0 + i) * H + k0 + threadIdx.x] = f2b(tile[threadIdx.x][i]);
}

// ---------- SpMM + residual: s = 0.8 * (A_hat h) + 0.2 * h0 (h is bf16) ----------
__global__ __launch_bounds__(256) void k_spmm(
    const u16* __restrict__ h, const float* __restrict__ h0,
    const int* __restrict__ offs, const int* __restrict__ col, const float* __restrict__ w,
    const float* __restrict__ dinv,
    float* __restrict__ s, u16* __restrict__ sb)
{
  int wid = threadIdx.x >> 6, lane = threadIdx.x & 63;
  int node = blockIdx.x * 4 + wid;
  if (node >= N_NODES) return;
  int c4 = lane * 4;
  float di = dinv[node];
  float di2 = di * di;
  ushort4 hv = *(const ushort4*)(h + (size_t)node * H + c4);  // self loop
  float ax = di2 * b2f(hv.x), ay = di2 * b2f(hv.y), az = di2 * b2f(hv.z), aw = di2 * b2f(hv.w);
  int e = offs[node], e1 = offs[node + 1];
  for (; e + 2 <= e1; e += 2) {
    int j0 = col[e], j1 = col[e + 1];
    float w0 = w[e], w1 = w[e + 1];
    ushort4 v0 = *(const ushort4*)(h + (size_t)j0 * H + c4);
    ushort4 v1 = *(const ushort4*)(h + (size_t)j1 * H + c4);
    ax += w0 * b2f(v0.x); ay += w0 * b2f(v0.y); az += w0 * b2f(v0.z); aw += w0 * b2f(v0.w);
    ax += w1 * b2f(v1.x); ay += w1 * b2f(v1.y); az += w1 * b2f(v1.z); aw += w1 * b2f(v1.w);
  }
  if (e < e1) {
    int j0 = col[e];
    float w0 = w[e];
    ushort4 v0 = *(const ushort4*)(h + (size_t)j0 * H + c4);
    ax += w0 * b2f(v0.x); ay += w0 * b2f(v0.y); az += w0 * b2f(v0.z); aw += w0 * b2f(v0.w);
  }
  float4 h0v = *(const float4*)(h0 + (size_t)node * H + c4);
  float4 sv;
  sv.x = (1.0f - ALPHA) * ax + ALPHA * h0v.x;
  sv.y = (1.0f - ALPHA) * ay + ALPHA * h0v.y;
  sv.z = (1.0f - ALPHA) * az + ALPHA * h0v.z;
  sv.w = (1.0f - ALPHA) * aw + ALPHA * h0v.w;
  *(float4*)(s + (size_t)node * H + c4) = sv;
  ushort4 sb4;
  sb4.x = f2b(sv.x); sb4.y = f2b(sv.y); sb4.z = f2b(sv.z); sb4.w = f2b(sv.w);
  *(ushort4*)(sb + (size_t)node * H + c4) = sb4;
}

// ---------- MFMA layer GEMM: h = relu((1-beta)*s + beta * (sb @ W)) ----------
// A = sb [M,256] bf16 row-major; BT = WT_l [256,256] bf16, BT[n][k] = W[k][n].
__global__ __launch_bounds__(256) void k_gemm(
    const u16* __restrict__ A, const u16* __restrict__ BT,
    const float* __restrict__ Sin, u16* __restrict__ Hout, float beta)
{
  __shared__ u16 As[128 * 40];  // row stride 40 u16 = 80 B
  __shared__ u16 Bs[128 * 40];
  int tid = threadIdx.x;
  int mBase = blockIdx.x * 128, nBase = blockIdx.y * 128;
  int wid = tid >> 6, lane = tid & 63;
  int wm = (wid & 1) * 64, wn = (wid >> 1) * 64;
  int lrow = lane & 15, quad = lane >> 4;
  f32x4 acc[4][4] = {};
  int sr = tid >> 2, sc = tid & 3;   // staging: row (0..63), 16B chunk (0..3)
  for (int k0 = 0; k0 < H; k0 += 32) {
#pragma unroll
    for (int it = 0; it < 2; ++it) {
      int r = sr + it * 64;
      int grow = mBase + r;
      u32x4 va = {};
      if (grow < N_NODES) va = *(const u32x4*)(A + (size_t)grow * H + k0 + sc * 8);
      *(u32x4*)&As[r * 40 + sc * 8] = va;
      u32x4 vb = *(const u32x4*)(BT + (size_t)(nBase + r) * H + k0 + sc * 8);
      *(u32x4*)&Bs[r * 40 + sc * 8] = vb;
    }
    __syncthreads();
    short8 af[4], bfr[4];
#pragma unroll
    for (int i = 0; i < 4; ++i) {
      af[i]  = *(const short8*)&As[(wm + i * 16 + lrow) * 40 + quad * 8];
      bfr[i] = *(const short8*)&Bs[(wn + i * 16 + lrow) * 40 + quad * 8];
    }
#pragma unroll
    for (int mi = 0; mi < 4; ++mi)
#pragma unroll
      for (int ni = 0; ni < 4; ++ni)
        acc[mi][ni] = __builtin_amdgcn_mfma_f32_16x16x32_bf16(af[mi], bfr[ni], acc[mi][ni], 0, 0, 0);
    __syncthreads();
  }
#pragma unroll
  for (int mi = 0; mi < 4; ++mi)
#pragma unroll
    for (int ni = 0; ni < 4; ++ni)
#pragma unroll
      for (int rg = 0; rg < 4; ++rg) {
        int r = mBase + wm + mi * 16 + quad * 4 + rg;  // C/D: row = quad*4+reg
        int c = nBase + wn + ni * 16 + lrow;           //      col = lane&15
        if (r < N_NODES) {
          size_t idx = (size_t)r * H + c;
          float v = (1.0f - beta) * Sin[idx] + beta * acc[mi][ni][rg];
          Hout[idx] = f2b(fmaxf(v, 0.0f));
        }
      }
}

// ---------- f32 VALU projection GEMM: h0 = x @ projW + b ; also bf16 h copy ----------
__global__ __launch_bounds__(256) void k_vgemm(
    const float* __restrict__ A, const float* __restrict__ W, int K,
    const float* __restrict__ bias, float* __restrict__ outF, u16* __restrict__ outB)
{
  __shared__ float As[16][68];
  __shared__ float Ws[16][68];
  int tid = threadIdx.x;
  int mBase = blockIdx.x * 64, nBase = blockIdx.y * 64;
  int ty4 = (tid >> 4) * 4;
  int tx4 = (tid & 15) * 4;
  int srow = tid >> 2;
  int skseg = (tid & 3) * 4;
  int wkk = tid >> 4;
  int wcseg = (tid & 15) * 4;
  float acc[4][4];
#pragma unroll
  for (int i = 0; i < 4; ++i)
#pragma unroll
    for (int j = 0; j < 4; ++j) acc[i][j] = 0.0f;

  for (int k0 = 0; k0 < K; k0 += 16) {
    float4 av4 = make_float4(0.f, 0.f, 0.f, 0.f);
    int grow = mBase + srow;
    if (grow < N_NODES) av4 = *(const float4*)(A + (size_t)grow * K + k0 + skseg);
    As[skseg + 0][srow] = av4.x;
    As[skseg + 1][srow] = av4.y;
    As[skseg + 2][srow] = av4.z;
    As[skseg + 3][srow] = av4.w;
    *(float4*)&Ws[wkk][wcseg] = *(const float4*)(W + (size_t)(k0 + wkk) * H + nBase + wcseg);
    __syncthreads();
#pragma unroll
    for (int kk = 0; kk < 16; ++kk) {
      float4 a4 = *(const float4*)&As[kk][ty4];
      float4 w4 = *(const float4*)&Ws[kk][tx4];
      float av[4] = {a4.x, a4.y, a4.z, a4.w};
      float wv[4] = {w4.x, w4.y, w4.z, w4.w};
#pragma unroll
      for (int i = 0; i < 4; ++i)
#pragma unroll
        for (int j = 0; j < 4; ++j) acc[i][j] += av[i] * wv[j];
    }
    __syncthreads();
  }

#pragma unroll
  for (int i = 0; i < 4; ++i) {
    int row = mBase + ty4 + i;
    if (row >= N_NODES) break;
#pragma unroll
    for (int j = 0; j < 4; ++j) {
      int colg = nBase + tx4 + j;
      size_t idx = (size_t)row * H + colg;
      float v = acc[i][j] + bias[colg];
      outF[idx] = v;
      outB[idx] = f2b(v);
    }
  }
}

// ---------- classifier: out[n, 0..3] = h[n,:] @ clsW + clsb (h bf16) ----------
__global__ __launch_bounds__(256) void k_cls(const u16* __restrict__ h,
    const float* __restrict__ W, const float* __restrict__ b, float* __restrict__ out)
{
  int wid = threadIdx.x >> 6, lane = threadIdx.x & 63;
  int node = blockIdx.x * 4 + wid;
  if (node >= N_NODES) return;
  float a0 = 0, a1 = 0, a2 = 0, a3 = 0;
  for (int t = lane; t < H; t += 64) {
    float hv = b2f(h[(size_t)node * H + t]);
    a0 += hv * W[t * 4 + 0];
    a1 += hv * W[t * 4 + 1];
    a2 += hv * W[t * 4 + 2];
    a3 += hv * W[t * 4 + 3];
  }
#pragma unroll
  for (int off = 32; off > 0; off >>= 1) {
    a0 += __shfl_down(a0, off);
    a1 += __shfl_down(a1, off);
    a2 += __shfl_down(a2, off);
    a3 += __shfl_down(a3, off);
  }
  if (lane == 0) {
    float4 o;
    o.x = a0 + b[0];
    o.y = a1 + b[1];
    o.z = a2 + b[2];
    o.w = a3 + b[3];
    *(float4*)(out + (size_t)node * 4) = o;
  }
}

extern "C" void kernel_launch(void* const* d_in, const int* in_sizes, int n_in,
                              void* d_out, int out_size, void* d_ws, size_t ws_size,
                              hipStream_t stream) {
  (void)in_sizes; (void)n_in; (void)out_size; (void)ws_size;
  const float* x     = (const float*)d_in[0];
  const int*   ei    = (const int*)d_in[1];
  const float* projW = (const float*)d_in[2];
  const float* projB = (const float*)d_in[3];
  const float* wts   = (const float*)d_in[4];
  const float* clsW  = (const float*)d_in[5];
  const float* clsB  = (const float*)d_in[6];
  float* out = (float*)d_out;

  char* ws = (char*)d_ws;
  size_t off = 0;
  auto alloc = [&](size_t bytes) -> void* {
    void* p = ws + off;
    off = (off + bytes + 255) & ~(size_t)255;
    return p;
  };
  int*   cntcur = (int*)alloc((size_t)N_NODES * 2 * 4);
  int*   cnt    = cntcur;
  int*   cursor = cntcur + N_NODES;
  int*   offs   = (int*)alloc((size_t)(N_NODES + 1) * 4);
  float* dinv   = (float*)alloc((size_t)N_NODES * 4);
  int*   col    = (int*)alloc((size_t)N_EDGES * 4);
  float* w      = (float*)alloc((size_t)N_EDGES * 4);
  u16*   WT     = (u16*)alloc((size_t)L_LAYERS * H * H * 2);
  float* h0     = (float*)alloc((size_t)N_NODES * H * 4);
  float* s      = (float*)alloc((size_t)N_NODES * H * 4);
  u16*   sb     = (u16*)alloc((size_t)N_NODES * H * 2);
  u16*   h      = (u16*)alloc((size_t)N_NODES * H * 2);

  const int* src = ei;
  const int* dst = ei + N_EDGES;

  k_zero<<<(N_NODES * 2 + 255) / 256, 256, 0, stream>>>(cntcur, N_NODES * 2);
  k_count<<<(N_EDGES + 255) / 256, 256, 0, stream>>>(dst, cnt);
  k_dinv<<<(N_NODES + 255) / 256, 256, 0, stream>>>(cnt, dinv);
  k_scan<<<1, 1024, 0, stream>>>(cnt, offs);
  k_scatter<<<(N_EDGES + 255) / 256, 256, 0, stream>>>(src, dst, offs, cursor, dinv, col, w);
  k_wtr<<<dim3(H / 32, H / 32, L_LAYERS), dim3(32, 8), 0, stream>>>(wts, WT);

  // projection: h0 (f32) + h (bf16) = x @ projW + b
  k_vgemm<<<dim3((N_NODES + 63) / 64, H / 64), 256, 0, stream>>>(x, projW, DIN, projB, h0, h);

  dim3 ggrid((N_NODES + 127) / 128, H / 128);
  for (int l = 0; l < L_LAYERS; ++l) {
    k_spmm<<<(N_NODES + 3) / 4, 256, 0, stream>>>(h, h0, offs, col, w, dinv, s, sb);
    float beta = logf(0.5f / (float)(l + 1) + 1.0f);
    k_gemm<<<ggrid, 256, 0, stream>>>(sb, WT + (size_t)l * H * H, s, h, beta);
  }
  k_cls<<<(N_NODES + 3) / 4, 256, 0, stream>>>(h, clsW, clsB, out);
}